// Round 1
// baseline (221.280 us; speedup 1.0000x reference)
//
#include <hip/hip_runtime.h>

#define TSEQ 1024
#define HIDV 64
#define NHEADS 16      // N*H = 2*8
#define D2 128         // 2*HID
#define LCH 128        // chunk length
#define NCH 8          // TSEQ/LCH
#define EMBED 512
#define CTX_FLOATS (NHEADS * TSEQ * HIDV)          // 1048576
#define PROBS_FLOATS ((size_t)NHEADS * TSEQ * TSEQ) // 16777216
#define EPSV 1e-6f
#define PIH 1.5707963267948966f

__device__ __forceinline__ float relu_f(float x) { return fmaxf(x, 0.0f); }

// ---------------------------------------------------------------------------
// Kernel 1: per (seq b, chunk c) compute S[d][m] = sum_i kw[i][d] * v[i][m]
// (kw = relu(k) weighted by sin/cos) and ksum[d] = sum_i kw[i][d].
// grid = 128 blocks (b*8+c), 256 threads.
// ---------------------------------------------------------------------------
__global__ __launch_bounds__(256) void k_chunksum(
    const float* __restrict__ K, const float* __restrict__ V,
    float* __restrict__ Sws, float* __restrict__ ksumws)
{
    __shared__ __align__(16) float kwl[LCH * 132];   // [i][d(128)+pad]
    __shared__ __align__(16) float vl[LCH * HIDV];   // [i][m]
    const int blk = blockIdx.x;
    const int b = blk >> 3, c = blk & 7;
    const int l0 = c * LCH;
    const int tid = threadIdx.x;

    // stage kw (weighted relu(k)) and v chunk
    #pragma unroll
    for (int s = 0; s < 8; ++s) {
        int flat = tid * 4 + s * 1024;     // covers 0..8191, i-major
        int i = flat >> 6, d = flat & 63;
        float4 k4 = *(const float4*)(K + (size_t)(b * TSEQ + l0 + i) * HIDV + d);
        k4.x = relu_f(k4.x); k4.y = relu_f(k4.y); k4.z = relu_f(k4.z); k4.w = relu_f(k4.w);
        float ang = PIH * (float)(l0 + i + 1) * (1.0f / 1024.0f);
        float si = sinf(ang), ci = cosf(ang);
        float4 a = make_float4(k4.x * si, k4.y * si, k4.z * si, k4.w * si);
        float4 bb = make_float4(k4.x * ci, k4.y * ci, k4.z * ci, k4.w * ci);
        *(float4*)(kwl + i * 132 + d) = a;
        *(float4*)(kwl + i * 132 + 64 + d) = bb;
        // v reinterpreted as (T, NH, HID)
        float4 v4 = *(const float4*)(V + ((size_t)(l0 + i) * NHEADS + b) * HIDV + d);
        *(float4*)(vl + i * HIDV + d) = v4;
    }
    __syncthreads();

    const int d0 = (tid >> 4) * 8;   // 16 groups of 8 d-rows
    const int m0 = (tid & 15) * 4;   // 16 groups of 4 m-cols
    float acc[8][4];
    #pragma unroll
    for (int r = 0; r < 8; ++r) { acc[r][0] = 0; acc[r][1] = 0; acc[r][2] = 0; acc[r][3] = 0; }

    for (int i = 0; i < LCH; ++i) {
        float4 v4 = *(const float4*)(vl + i * HIDV + m0);
        float4 ka = *(const float4*)(kwl + i * 132 + d0);
        float4 kb = *(const float4*)(kwl + i * 132 + d0 + 4);
        float kvv[8] = {ka.x, ka.y, ka.z, ka.w, kb.x, kb.y, kb.z, kb.w};
        #pragma unroll
        for (int r = 0; r < 8; ++r) {
            acc[r][0] = fmaf(kvv[r], v4.x, acc[r][0]);
            acc[r][1] = fmaf(kvv[r], v4.y, acc[r][1]);
            acc[r][2] = fmaf(kvv[r], v4.z, acc[r][2]);
            acc[r][3] = fmaf(kvv[r], v4.w, acc[r][3]);
        }
    }
    float* Sp = Sws + (size_t)blk * (D2 * HIDV);
    #pragma unroll
    for (int r = 0; r < 8; ++r) {
        float4 o = make_float4(acc[r][0], acc[r][1], acc[r][2], acc[r][3]);
        *(float4*)(Sp + (d0 + r) * HIDV + m0) = o;
    }
    if (tid < D2) {
        float s = 0;
        for (int i = 0; i < LCH; ++i) s += kwl[i * 132 + tid];
        ksumws[(size_t)blk * D2 + tid] = s;
    }
}

// ---------------------------------------------------------------------------
// Kernel 2: per (seq, chunk): A = tril(cos(di-dj) * Qr Kr^T); O = A*V + inter
// via prefix state P; divide by denominator; write attn in (T, N, 512) layout.
// grid = 128 blocks, 256 threads. LDS ~134 KB -> 1 block/CU.
// ---------------------------------------------------------------------------
__global__ __launch_bounds__(256) void k_attn(
    const float* __restrict__ Q, const float* __restrict__ K,
    const float* __restrict__ V,
    const float* __restrict__ Sws, const float* __restrict__ ksumws,
    float* __restrict__ attn2)
{
    __shared__ __align__(16) float qrT[64 * 132];    // [d][i(128)+pad]
    __shared__ __align__(16) float slot2[64 * 132];  // krT -> P[128*64] -> v[128*64]
    __shared__ __align__(16) float AT[LCH * 132];    // [j][i(128)+pad], weighted+masked
    __shared__ float sA[128], cAr[128], den_l[128], psum_l[128];

    const int blk = blockIdx.x;
    const int b = blk >> 3, c = blk & 7;
    const int l0 = c * LCH;
    const int tid = threadIdx.x;

    // stage qrT, krT (transposed, relu applied)
    #pragma unroll
    for (int s = 0; s < 8; ++s) {
        int flat = tid * 4 + s * 1024;
        int i = flat >> 6, d = flat & 63;
        float4 q4 = *(const float4*)(Q + (size_t)(b * TSEQ + l0 + i) * HIDV + d);
        qrT[(d + 0) * 132 + i] = relu_f(q4.x);
        qrT[(d + 1) * 132 + i] = relu_f(q4.y);
        qrT[(d + 2) * 132 + i] = relu_f(q4.z);
        qrT[(d + 3) * 132 + i] = relu_f(q4.w);
        float4 k4 = *(const float4*)(K + (size_t)(b * TSEQ + l0 + i) * HIDV + d);
        slot2[(d + 0) * 132 + i] = relu_f(k4.x);
        slot2[(d + 1) * 132 + i] = relu_f(k4.y);
        slot2[(d + 2) * 132 + i] = relu_f(k4.z);
        slot2[(d + 3) * 132 + i] = relu_f(k4.w);
    }
    if (tid < 128) {
        float ang = PIH * (float)(l0 + tid + 1) * (1.0f / 1024.0f);
        sA[tid] = sinf(ang);
        cAr[tid] = cosf(ang);
    }
    __syncthreads();

    const int i0 = (tid >> 4) * 8;
    const int j0 = (tid & 15) * 8;

    // Phase A: A-matrix (8x8 per thread), store transposed AT[j][i], masked j<=i
    {
        float a[8][8];
        #pragma unroll
        for (int ri = 0; ri < 8; ++ri)
            #pragma unroll
            for (int rj = 0; rj < 8; ++rj) a[ri][rj] = 0;

        for (int d = 0; d < 64; ++d) {
            float4 qa = *(const float4*)(qrT + d * 132 + i0);
            float4 qb = *(const float4*)(qrT + d * 132 + i0 + 4);
            float4 ka = *(const float4*)(slot2 + d * 132 + j0);
            float4 kb = *(const float4*)(slot2 + d * 132 + j0 + 4);
            float qv[8] = {qa.x, qa.y, qa.z, qa.w, qb.x, qb.y, qb.z, qb.w};
            float kv[8] = {ka.x, ka.y, ka.z, ka.w, kb.x, kb.y, kb.z, kb.w};
            #pragma unroll
            for (int ri = 0; ri < 8; ++ri)
                #pragma unroll
                for (int rj = 0; rj < 8; ++rj)
                    a[ri][rj] = fmaf(qv[ri], kv[rj], a[ri][rj]);
        }
        #pragma unroll
        for (int rj = 0; rj < 8; ++rj) {
            int j = j0 + rj;
            float sj = sA[j], cj = cAr[j];
            #pragma unroll
            for (int ri = 0; ri < 8; ++ri) {
                int i = i0 + ri;
                float w = (j <= i) ? fmaf(sA[i], sj, cAr[i] * cj) : 0.0f;
                AT[j * 132 + i] = w * a[ri][rj];
            }
        }
    }
    __syncthreads();

    // Load prefix P (sum of previous chunks' S) into slot2, psum into psum_l
    {
        const float* Sb = Sws + (size_t)b * NCH * (D2 * HIDV);
        for (int idx = tid; idx < D2 * HIDV; idx += 256) {
            float accp = 0;
            for (int cp = 0; cp < c; ++cp) accp += Sb[(size_t)cp * (D2 * HIDV) + idx];
            slot2[idx] = accp;    // P[d*64+m]
        }
        if (tid < D2) {
            const float* Kb = ksumws + (size_t)b * NCH * D2;
            float accp = 0;
            for (int cp = 0; cp < c; ++cp) accp += Kb[cp * D2 + tid];
            psum_l[tid] = accp;
        }
    }
    __syncthreads();

    // inter-chunk denominator part
    if (tid < 128) {
        const int i = tid;
        float st = 0, sb2 = 0;
        for (int d = 0; d < 64; ++d) {
            float qv = qrT[d * 132 + i];
            st = fmaf(qv, psum_l[d], st);
            sb2 = fmaf(qv, psum_l[64 + d], sb2);
        }
        den_l[i] = sA[i] * st + cAr[i] * sb2;
    }

    // Phase B: inter-chunk numerator X = Qr*P_top, Y = Qr*P_bot (8 rows x 4 m)
    const int m0 = (tid & 15) * 4;
    float X[8][4], Y[8][4];
    #pragma unroll
    for (int r = 0; r < 8; ++r) {
        X[r][0] = X[r][1] = X[r][2] = X[r][3] = 0;
        Y[r][0] = Y[r][1] = Y[r][2] = Y[r][3] = 0;
    }
    for (int d = 0; d < 64; ++d) {
        float4 qa = *(const float4*)(qrT + d * 132 + i0);
        float4 qb = *(const float4*)(qrT + d * 132 + i0 + 4);
        float4 pt = *(const float4*)(slot2 + d * HIDV + m0);
        float4 pb = *(const float4*)(slot2 + (d + 64) * HIDV + m0);
        float qv[8] = {qa.x, qa.y, qa.z, qa.w, qb.x, qb.y, qb.z, qb.w};
        #pragma unroll
        for (int r = 0; r < 8; ++r) {
            X[r][0] = fmaf(qv[r], pt.x, X[r][0]);
            X[r][1] = fmaf(qv[r], pt.y, X[r][1]);
            X[r][2] = fmaf(qv[r], pt.z, X[r][2]);
            X[r][3] = fmaf(qv[r], pt.w, X[r][3]);
            Y[r][0] = fmaf(qv[r], pb.x, Y[r][0]);
            Y[r][1] = fmaf(qv[r], pb.y, Y[r][1]);
            Y[r][2] = fmaf(qv[r], pb.z, Y[r][2]);
            Y[r][3] = fmaf(qv[r], pb.w, Y[r][3]);
        }
    }
    __syncthreads();

    // load v chunk into slot2; finish denominators (A row sums; AT zero-filled above diag)
    #pragma unroll
    for (int s = 0; s < 8; ++s) {
        int flat = tid * 4 + s * 1024;
        int i = flat >> 6, m = flat & 63;
        float4 v4 = *(const float4*)(V + ((size_t)(l0 + i) * NHEADS + b) * HIDV + m);
        *(float4*)(slot2 + i * HIDV + m) = v4;
    }
    if (tid < 128) {
        float rs = 0;
        for (int j = 0; j < 128; ++j) rs += AT[j * 132 + tid];
        den_l[tid] = fmaxf(den_l[tid] + rs, EPSV);
    }
    __syncthreads();

    // Phase C: O = s_i*X + c_i*Y + tril(A)*V, divide, write
    float O[8][4];
    #pragma unroll
    for (int r = 0; r < 8; ++r) {
        float si = sA[i0 + r], ci = cAr[i0 + r];
        O[r][0] = si * X[r][0] + ci * Y[r][0];
        O[r][1] = si * X[r][1] + ci * Y[r][1];
        O[r][2] = si * X[r][2] + ci * Y[r][2];
        O[r][3] = si * X[r][3] + ci * Y[r][3];
    }
    for (int j = 0; j < 128; ++j) {
        float4 aa = *(const float4*)(AT + j * 132 + i0);
        float4 ab = *(const float4*)(AT + j * 132 + i0 + 4);
        float4 v4 = *(const float4*)(slot2 + j * HIDV + m0);
        float av[8] = {aa.x, aa.y, aa.z, aa.w, ab.x, ab.y, ab.z, ab.w};
        #pragma unroll
        for (int r = 0; r < 8; ++r) {
            O[r][0] = fmaf(av[r], v4.x, O[r][0]);
            O[r][1] = fmaf(av[r], v4.y, O[r][1]);
            O[r][2] = fmaf(av[r], v4.z, O[r][2]);
            O[r][3] = fmaf(av[r], v4.w, O[r][3]);
        }
    }
    const int nb = b >> 3, hh = b & 7;
    #pragma unroll
    for (int r = 0; r < 8; ++r) {
        int i = i0 + r;
        float inv = 1.0f / den_l[i];
        float4 o = make_float4(O[r][0] * inv, O[r][1] * inv, O[r][2] * inv, O[r][3] * inv);
        size_t row = (size_t)((l0 + i) * 2 + nb);   // (t, n) row in attn2
        *(float4*)(attn2 + row * EMBED + hh * HIDV + m0) = o;
    }
}

// ---------------------------------------------------------------------------
// Kernel 3: out projection. out[r][e] = sum_f attn2[r][f]*W[e][f] + b[e],
// scattered to context (N,H,T,HID). grid = (32, 8), 64x64 tiles, 4x4/thread.
// ---------------------------------------------------------------------------
__global__ __launch_bounds__(256) void k_outproj(
    const float* __restrict__ A2, const float* __restrict__ W,
    const float* __restrict__ bias, float* __restrict__ ctx)
{
    __shared__ __align__(16) float AlT[64 * 68];  // [f][r+pad]
    __shared__ __align__(16) float WlT[64 * 68];  // [f][e+pad]
    const int r0 = blockIdx.x * 64;
    const int e0 = blockIdx.y * 64;
    const int tid = threadIdx.x;
    const int rr0 = (tid >> 4) * 4;
    const int ee0 = (tid & 15) * 4;
    float acc[4][4];
    #pragma unroll
    for (int r = 0; r < 4; ++r) { acc[r][0] = 0; acc[r][1] = 0; acc[r][2] = 0; acc[r][3] = 0; }

    for (int f0 = 0; f0 < EMBED; f0 += 64) {
        __syncthreads();
        #pragma unroll
        for (int s = 0; s < 4; ++s) {
            int flat = tid * 4 + s * 1024;
            int rr = flat >> 6, ff = flat & 63;
            float4 a4 = *(const float4*)(A2 + (size_t)(r0 + rr) * EMBED + f0 + ff);
            AlT[(ff + 0) * 68 + rr] = a4.x;
            AlT[(ff + 1) * 68 + rr] = a4.y;
            AlT[(ff + 2) * 68 + rr] = a4.z;
            AlT[(ff + 3) * 68 + rr] = a4.w;
            float4 w4 = *(const float4*)(W + (size_t)(e0 + rr) * EMBED + f0 + ff);
            WlT[(ff + 0) * 68 + rr] = w4.x;
            WlT[(ff + 1) * 68 + rr] = w4.y;
            WlT[(ff + 2) * 68 + rr] = w4.z;
            WlT[(ff + 3) * 68 + rr] = w4.w;
        }
        __syncthreads();
        for (int f = 0; f < 64; ++f) {
            float4 a4 = *(const float4*)(AlT + f * 68 + rr0);
            float4 w4 = *(const float4*)(WlT + f * 68 + ee0);
            float av[4] = {a4.x, a4.y, a4.z, a4.w};
            float wv[4] = {w4.x, w4.y, w4.z, w4.w};
            #pragma unroll
            for (int r = 0; r < 4; ++r) {
                acc[r][0] = fmaf(av[r], wv[0], acc[r][0]);
                acc[r][1] = fmaf(av[r], wv[1], acc[r][1]);
                acc[r][2] = fmaf(av[r], wv[2], acc[r][2]);
                acc[r][3] = fmaf(av[r], wv[3], acc[r][3]);
            }
        }
    }
    const int e = e0 + ee0;
    const int h = e >> 6, m = e & 63;
    float4 bo = *(const float4*)(bias + e);
    #pragma unroll
    for (int rr = 0; rr < 4; ++rr) {
        int r = r0 + rr0 + rr;
        int t = r >> 1, n = r & 1;
        float4 o = make_float4(acc[rr][0] + bo.x, acc[rr][1] + bo.y,
                               acc[rr][2] + bo.z, acc[rr][3] + bo.w);
        *(float4*)(ctx + ((size_t)(n * 8 + h) * TSEQ + t) * HIDV + m) = o;
    }
}

// ---------------------------------------------------------------------------
extern "C" void kernel_launch(void* const* d_in, const int* in_sizes, int n_in,
                              void* d_out, int out_size, void* d_ws, size_t ws_size,
                              hipStream_t stream) {
    const float* q = (const float*)d_in[0];
    const float* k = (const float*)d_in[1];
    const float* v = (const float*)d_in[2];
    const float* W = (const float*)d_in[3];
    const float* bias = (const float*)d_in[4];
    float* out = (float*)d_out;
    float* ws = (float*)d_ws;

    float* S_ws = ws;                                   // 16*8*8192  = 1048576 floats
    float* ksum_ws = ws + 1048576;                      // 16*8*128   = 16384 floats
    float* attn2 = ws + 1048576 + 16384;                // 2048*512   = 1048576 floats

    // probs output = zeros (context region is fully overwritten by k_outproj)
    hipMemsetAsync(out + CTX_FLOATS, 0, PROBS_FLOATS * sizeof(float), stream);

    k_chunksum<<<dim3(128), dim3(256), 0, stream>>>(k, v, S_ws, ksum_ws);
    k_attn<<<dim3(128), dim3(256), 0, stream>>>(q, k, v, S_ws, ksum_ws, attn2);
    k_outproj<<<dim3(32, 8), dim3(256), 0, stream>>>(attn2, W, bias, out);
}

// Round 2
// 201.099 us; speedup vs baseline: 1.1004x; 1.1004x over previous
//
#include <hip/hip_runtime.h>

#define TSEQ 1024
#define HIDV 64
#define NHEADS 16      // N*H = 2*8
#define LCH 64         // chunk length
#define NCH 16         // TSEQ/LCH
#define EMBED 512
#define CTX_FLOATS (NHEADS * TSEQ * HIDV)           // 1048576
#define PROBS_FLOATS ((size_t)NHEADS * TSEQ * TSEQ) // 16777216
#define EPSV 1e-6f
#define PIH 1.5707963267948966f

__device__ __forceinline__ float relu_f(float x) { return fmaxf(x, 0.0f); }

// ---------------------------------------------------------------------------
// Kernel 1: per (seq b, chunk c): S[d][m] = sum_i w_i(d) relu(k)[i][d%64] v[i][m]
// (w = sin for d<64, cos for d>=64) and ksum[d] = sum_i w_i(d) relu(k)[i][d%64].
// grid = 256 blocks (b*16+c), 512 threads.
// ---------------------------------------------------------------------------
__global__ __launch_bounds__(512) void k_chunksum(
    const float* __restrict__ K, const float* __restrict__ V,
    float* __restrict__ Sws, float* __restrict__ ksumws)
{
    __shared__ __align__(16) float kr[64 * 68];   // [i][d], relu'd, unweighted
    __shared__ __align__(16) float vl[64 * 64];   // [i][m]
    __shared__ float sA[64], cA[64];
    const int blk = blockIdx.x;
    const int b = blk >> 4, c = blk & 15;
    const int l0 = c * LCH;
    const int tid = threadIdx.x;

    #pragma unroll
    for (int s = 0; s < 2; ++s) {
        int flat = tid * 4 + s * 2048;
        int i = flat >> 6, d = flat & 63;
        float4 k4 = *(const float4*)(K + (size_t)(b * TSEQ + l0 + i) * HIDV + d);
        k4.x = relu_f(k4.x); k4.y = relu_f(k4.y); k4.z = relu_f(k4.z); k4.w = relu_f(k4.w);
        *(float4*)(kr + i * 68 + d) = k4;
        float4 v4 = *(const float4*)(V + ((size_t)(l0 + i) * NHEADS + b) * HIDV + d);
        *(float4*)(vl + i * 64 + d) = v4;
    }
    if (tid < 64) {
        float ang = PIH * (float)(l0 + tid + 1) * (1.0f / 1024.0f);
        sA[tid] = sinf(ang);
        cA[tid] = cosf(ang);
    }
    __syncthreads();

    const int d0 = (tid >> 4) * 4;   // 0..124 (32 groups)
    const int m0 = (tid & 15) * 4;   // 0..60
    const bool top = d0 < 64;        // wave-uniform
    const int dk = top ? d0 : (d0 - 64);
    float acc[4][4] = {};

    for (int i = 0; i < 64; ++i) {
        float w = top ? sA[i] : cA[i];
        float4 k4 = *(const float4*)(kr + i * 68 + dk);
        float4 v4 = *(const float4*)(vl + i * 64 + m0);
        float wk[4] = {w * k4.x, w * k4.y, w * k4.z, w * k4.w};
        #pragma unroll
        for (int r = 0; r < 4; ++r) {
            acc[r][0] = fmaf(wk[r], v4.x, acc[r][0]);
            acc[r][1] = fmaf(wk[r], v4.y, acc[r][1]);
            acc[r][2] = fmaf(wk[r], v4.z, acc[r][2]);
            acc[r][3] = fmaf(wk[r], v4.w, acc[r][3]);
        }
    }
    float* Sp = Sws + (size_t)blk * 8192;
    #pragma unroll
    for (int r = 0; r < 4; ++r) {
        float4 o = make_float4(acc[r][0], acc[r][1], acc[r][2], acc[r][3]);
        *(float4*)(Sp + (d0 + r) * 64 + m0) = o;
    }
    if (tid < 128) {
        int d = tid;
        bool tp = d < 64;
        int dk2 = d & 63;
        float s = 0;
        for (int i = 0; i < 64; ++i) s += (tp ? sA[i] : cA[i]) * kr[i * 68 + dk2];
        ksumws[(size_t)blk * 128 + d] = s;
    }
}

// ---------------------------------------------------------------------------
// Kernel 2: in-place exclusive prefix scan over chunks: Sws[b][c] -> sum_{c'<c},
// same for ksumws. grid = 512 blocks x 256 threads (one thread per (b, idx)).
// ---------------------------------------------------------------------------
__global__ __launch_bounds__(256) void k_scan(
    float* __restrict__ Sws, float* __restrict__ ksumws)
{
    int g = blockIdx.x * 256 + threadIdx.x;      // 0 .. 131071
    int b = g >> 13, idx = g & 8191;
    float acc = 0.0f;
    #pragma unroll
    for (int c = 0; c < NCH; ++c) {
        float* p = Sws + ((size_t)(b * NCH + c)) * 8192 + idx;
        float t = *p; *p = acc; acc += t;
    }
    if (g < NHEADS * 128) {
        int b2 = g >> 7, i2 = g & 127;
        float a2 = 0.0f;
        #pragma unroll
        for (int c = 0; c < NCH; ++c) {
            float* p = ksumws + (size_t)(b2 * NCH + c) * 128 + i2;
            float t = *p; *p = a2; a2 += t;
        }
    }
}

// ---------------------------------------------------------------------------
// Kernel 3: per (seq, chunk c of 64): A = tril(cos(di-dj) * Qr Kr^T);
// O = A*V + s_i*(Qr P_top) + c_i*(Qr P_bot); divide by denom; write (T,N,512).
// grid = 256 blocks, 512 threads. LDS ~68 KB.
// ---------------------------------------------------------------------------
__global__ __launch_bounds__(512) void k_attn(
    const float* __restrict__ Q, const float* __restrict__ K,
    const float* __restrict__ V,
    const float* __restrict__ Sws, const float* __restrict__ ksumws,
    float* __restrict__ attn2)
{
    __shared__ __align__(16) float qr[64 * 68];    // [i][d], relu'd
    __shared__ __align__(16) float big[8192];      // kr[64*68] -> P[128*64] -> V[64*64]
    __shared__ __align__(16) float Amat[64 * 68];  // [i][j], weighted+masked
    __shared__ float sA[64], cA[64], denA[64], denI[64], psum[128];

    const int blk = blockIdx.x;
    const int b = blk >> 4, c = blk & 15;
    const int l0 = c * LCH;
    const int tid = threadIdx.x;

    // stage qr, kr (row-major, relu)
    #pragma unroll
    for (int s = 0; s < 2; ++s) {
        int flat = tid * 4 + s * 2048;
        int i = flat >> 6, d = flat & 63;
        float4 q4 = *(const float4*)(Q + (size_t)(b * TSEQ + l0 + i) * HIDV + d);
        q4.x = relu_f(q4.x); q4.y = relu_f(q4.y); q4.z = relu_f(q4.z); q4.w = relu_f(q4.w);
        *(float4*)(qr + i * 68 + d) = q4;
        float4 k4 = *(const float4*)(K + (size_t)(b * TSEQ + l0 + i) * HIDV + d);
        k4.x = relu_f(k4.x); k4.y = relu_f(k4.y); k4.z = relu_f(k4.z); k4.w = relu_f(k4.w);
        *(float4*)(big + i * 68 + d) = k4;
    }
    if (tid < 64) {
        float ang = PIH * (float)(l0 + tid + 1) * (1.0f / 1024.0f);
        sA[tid] = sinf(ang);
        cA[tid] = cosf(ang);
    }
    __syncthreads();

    // Phase A: a[2][4] = Qr Kr^T partial tile; thread rows i0,i0+1; cols jt+16*jj
    const int i0 = (tid >> 4) * 2;   // 0..62
    const int jt = tid & 15;
    float a[2][4] = {};
    for (int d = 0; d < 64; d += 4) {
        float4 q0 = *(const float4*)(qr + i0 * 68 + d);
        float4 q1 = *(const float4*)(qr + (i0 + 1) * 68 + d);
        #pragma unroll
        for (int jj = 0; jj < 4; ++jj) {
            float4 k4 = *(const float4*)(big + (jt + 16 * jj) * 68 + d);
            a[0][jj] = fmaf(q0.x, k4.x, fmaf(q0.y, k4.y, fmaf(q0.z, k4.z, fmaf(q0.w, k4.w, a[0][jj]))));
            a[1][jj] = fmaf(q1.x, k4.x, fmaf(q1.y, k4.y, fmaf(q1.z, k4.z, fmaf(q1.w, k4.w, a[1][jj]))));
        }
    }
    // weight + mask + store + row-sums (reduce over the 16 j-groups via shuffle)
    {
        float rs[2];
        #pragma unroll
        for (int r = 0; r < 2; ++r) {
            int i = i0 + r;
            float si = sA[i], ci = cA[i];
            float rsum = 0.0f;
            #pragma unroll
            for (int jj = 0; jj < 4; ++jj) {
                int j = jt + 16 * jj;
                float w = (j <= i) ? fmaf(si, sA[j], ci * cA[j]) : 0.0f;
                float val = w * a[r][jj];
                Amat[i * 68 + j] = val;
                rsum += val;
            }
            rs[r] = rsum;
        }
        #pragma unroll
        for (int off = 1; off < 16; off <<= 1) {
            rs[0] += __shfl_xor(rs[0], off);
            rs[1] += __shfl_xor(rs[1], off);
        }
        if (jt == 0) { denA[i0] = rs[0]; denA[i0 + 1] = rs[1]; }
    }
    __syncthreads();

    // stage P (exclusive prefix, precomputed) and psum
    {
        const float* Pg = Sws + (size_t)blk * 8192;
        #pragma unroll
        for (int s = 0; s < 4; ++s) {
            int idx = tid * 4 + s * 2048;
            *(float4*)(big + idx) = *(const float4*)(Pg + idx);
        }
        if (tid < 128) psum[tid] = ksumws[(size_t)blk * 128 + tid];
    }
    __syncthreads();

    // Phase B: X = Qr P_top, Y = Qr P_bot (rows i0..i0+1, cols m0..m0+3)
    const int m0 = (tid & 15) * 4;
    float X[2][4] = {}, Y[2][4] = {};
    for (int d = 0; d < 64; ++d) {
        float q0 = qr[i0 * 68 + d];
        float q1 = qr[(i0 + 1) * 68 + d];
        float4 pt = *(const float4*)(big + d * 64 + m0);
        float4 pb = *(const float4*)(big + (64 + d) * 64 + m0);
        X[0][0] = fmaf(q0, pt.x, X[0][0]); X[0][1] = fmaf(q0, pt.y, X[0][1]);
        X[0][2] = fmaf(q0, pt.z, X[0][2]); X[0][3] = fmaf(q0, pt.w, X[0][3]);
        X[1][0] = fmaf(q1, pt.x, X[1][0]); X[1][1] = fmaf(q1, pt.y, X[1][1]);
        X[1][2] = fmaf(q1, pt.z, X[1][2]); X[1][3] = fmaf(q1, pt.w, X[1][3]);
        Y[0][0] = fmaf(q0, pb.x, Y[0][0]); Y[0][1] = fmaf(q0, pb.y, Y[0][1]);
        Y[0][2] = fmaf(q0, pb.z, Y[0][2]); Y[0][3] = fmaf(q0, pb.w, Y[0][3]);
        Y[1][0] = fmaf(q1, pb.x, Y[1][0]); Y[1][1] = fmaf(q1, pb.y, Y[1][1]);
        Y[1][2] = fmaf(q1, pb.z, Y[1][2]); Y[1][3] = fmaf(q1, pb.w, Y[1][3]);
    }
    // inter-chunk denominator
    if (tid < 64) {
        int i = tid;
        float st = 0, sb = 0;
        for (int d = 0; d < 64; ++d) {
            float qv = qr[i * 68 + d];
            st = fmaf(qv, psum[d], st);
            sb = fmaf(qv, psum[64 + d], sb);
        }
        denI[i] = sA[i] * st + cA[i] * sb;
    }
    __syncthreads();

    // stage V (reuse big; P dead)
    #pragma unroll
    for (int s = 0; s < 2; ++s) {
        int flat = tid * 4 + s * 2048;
        int i = flat >> 6, m = flat & 63;
        float4 v4 = *(const float4*)(V + ((size_t)(l0 + i) * NHEADS + b) * HIDV + m);
        *(float4*)(big + i * 64 + m) = v4;
    }
    __syncthreads();

    // Phase C: O = s_i X + c_i Y + tril(A) V; divide; write
    float O[2][4];
    #pragma unroll
    for (int r = 0; r < 2; ++r) {
        float si = sA[i0 + r], ci = cA[i0 + r];
        O[r][0] = si * X[r][0] + ci * Y[r][0];
        O[r][1] = si * X[r][1] + ci * Y[r][1];
        O[r][2] = si * X[r][2] + ci * Y[r][2];
        O[r][3] = si * X[r][3] + ci * Y[r][3];
    }
    for (int j = 0; j < 64; j += 4) {
        float4 a0 = *(const float4*)(Amat + i0 * 68 + j);
        float4 a1 = *(const float4*)(Amat + (i0 + 1) * 68 + j);
        float4 v0 = *(const float4*)(big + (j + 0) * 64 + m0);
        float4 v1 = *(const float4*)(big + (j + 1) * 64 + m0);
        float4 v2 = *(const float4*)(big + (j + 2) * 64 + m0);
        float4 v3 = *(const float4*)(big + (j + 3) * 64 + m0);
        O[0][0] = fmaf(a0.x, v0.x, fmaf(a0.y, v1.x, fmaf(a0.z, v2.x, fmaf(a0.w, v3.x, O[0][0]))));
        O[0][1] = fmaf(a0.x, v0.y, fmaf(a0.y, v1.y, fmaf(a0.z, v2.y, fmaf(a0.w, v3.y, O[0][1]))));
        O[0][2] = fmaf(a0.x, v0.z, fmaf(a0.y, v1.z, fmaf(a0.z, v2.z, fmaf(a0.w, v3.z, O[0][2]))));
        O[0][3] = fmaf(a0.x, v0.w, fmaf(a0.y, v1.w, fmaf(a0.z, v2.w, fmaf(a0.w, v3.w, O[0][3]))));
        O[1][0] = fmaf(a1.x, v0.x, fmaf(a1.y, v1.x, fmaf(a1.z, v2.x, fmaf(a1.w, v3.x, O[1][0]))));
        O[1][1] = fmaf(a1.x, v0.y, fmaf(a1.y, v1.y, fmaf(a1.z, v2.y, fmaf(a1.w, v3.y, O[1][1]))));
        O[1][2] = fmaf(a1.x, v0.z, fmaf(a1.y, v1.z, fmaf(a1.z, v2.z, fmaf(a1.w, v3.z, O[1][2]))));
        O[1][3] = fmaf(a1.x, v0.w, fmaf(a1.y, v1.w, fmaf(a1.z, v2.w, fmaf(a1.w, v3.w, O[1][3]))));
    }
    const int nb = b >> 3, hh = b & 7;
    #pragma unroll
    for (int r = 0; r < 2; ++r) {
        int i = i0 + r;
        float inv = 1.0f / fmaxf(denA[i] + denI[i], EPSV);
        float4 o = make_float4(O[r][0] * inv, O[r][1] * inv, O[r][2] * inv, O[r][3] * inv);
        size_t row = (size_t)((l0 + i) * 2 + nb);
        *(float4*)(attn2 + row * EMBED + hh * 64 + m0) = o;
    }
}

// ---------------------------------------------------------------------------
// Kernel 4: out projection (unchanged from R1 to isolate its cost).
// ---------------------------------------------------------------------------
__global__ __launch_bounds__(256) void k_outproj(
    const float* __restrict__ A2, const float* __restrict__ W,
    const float* __restrict__ bias, float* __restrict__ ctx)
{
    __shared__ __align__(16) float AlT[64 * 68];  // [f][r+pad]
    __shared__ __align__(16) float WlT[64 * 68];  // [f][e+pad]
    const int r0 = blockIdx.x * 64;
    const int e0 = blockIdx.y * 64;
    const int tid = threadIdx.x;
    const int rr0 = (tid >> 4) * 4;
    const int ee0 = (tid & 15) * 4;
    float acc[4][4];
    #pragma unroll
    for (int r = 0; r < 4; ++r) { acc[r][0] = 0; acc[r][1] = 0; acc[r][2] = 0; acc[r][3] = 0; }

    for (int f0 = 0; f0 < EMBED; f0 += 64) {
        __syncthreads();
        #pragma unroll
        for (int s = 0; s < 4; ++s) {
            int flat = tid * 4 + s * 1024;
            int rr = flat >> 6, ff = flat & 63;
            float4 a4 = *(const float4*)(A2 + (size_t)(r0 + rr) * EMBED + f0 + ff);
            AlT[(ff + 0) * 68 + rr] = a4.x;
            AlT[(ff + 1) * 68 + rr] = a4.y;
            AlT[(ff + 2) * 68 + rr] = a4.z;
            AlT[(ff + 3) * 68 + rr] = a4.w;
            float4 w4 = *(const float4*)(W + (size_t)(e0 + rr) * EMBED + f0 + ff);
            WlT[(ff + 0) * 68 + rr] = w4.x;
            WlT[(ff + 1) * 68 + rr] = w4.y;
            WlT[(ff + 2) * 68 + rr] = w4.z;
            WlT[(ff + 3) * 68 + rr] = w4.w;
        }
        __syncthreads();
        for (int f = 0; f < 64; ++f) {
            float4 a4 = *(const float4*)(AlT + f * 68 + rr0);
            float4 w4 = *(const float4*)(WlT + f * 68 + ee0);
            float av[4] = {a4.x, a4.y, a4.z, a4.w};
            float wv[4] = {w4.x, w4.y, w4.z, w4.w};
            #pragma unroll
            for (int r = 0; r < 4; ++r) {
                acc[r][0] = fmaf(av[r], wv[0], acc[r][0]);
                acc[r][1] = fmaf(av[r], wv[1], acc[r][1]);
                acc[r][2] = fmaf(av[r], wv[2], acc[r][2]);
                acc[r][3] = fmaf(av[r], wv[3], acc[r][3]);
            }
        }
    }
    const int e = e0 + ee0;
    const int h = e >> 6, m = e & 63;
    float4 bo = *(const float4*)(bias + e);
    #pragma unroll
    for (int rr = 0; rr < 4; ++rr) {
        int r = r0 + rr0 + rr;
        int t = r >> 1, n = r & 1;
        float4 o = make_float4(acc[rr][0] + bo.x, acc[rr][1] + bo.y,
                               acc[rr][2] + bo.z, acc[rr][3] + bo.w);
        *(float4*)(ctx + ((size_t)(n * 8 + h) * TSEQ + t) * HIDV + m) = o;
    }
}

// ---------------------------------------------------------------------------
extern "C" void kernel_launch(void* const* d_in, const int* in_sizes, int n_in,
                              void* d_out, int out_size, void* d_ws, size_t ws_size,
                              hipStream_t stream) {
    const float* q = (const float*)d_in[0];
    const float* k = (const float*)d_in[1];
    const float* v = (const float*)d_in[2];
    const float* W = (const float*)d_in[3];
    const float* bias = (const float*)d_in[4];
    float* out = (float*)d_out;
    float* ws = (float*)d_ws;

    float* S_ws = ws;                         // 16*16*8192 = 2097152 floats
    float* ksum_ws = ws + 2097152;            // 16*16*128  = 32768 floats
    float* attn2 = ws + 2097152 + 32768;      // 2048*512   = 1048576 floats

    hipMemsetAsync(out + CTX_FLOATS, 0, PROBS_FLOATS * sizeof(float), stream);

    k_chunksum<<<dim3(256), dim3(512), 0, stream>>>(k, v, S_ws, ksum_ws);
    k_scan<<<dim3(512), dim3(256), 0, stream>>>(S_ws, ksum_ws);
    k_attn<<<dim3(256), dim3(512), 0, stream>>>(q, k, v, S_ws, ksum_ws, attn2);
    k_outproj<<<dim3(32, 8), dim3(256), 0, stream>>>(attn2, W, bias, out);
}

// Round 3
// 121.356 us; speedup vs baseline: 1.8234x; 1.6571x over previous
//
#include <hip/hip_runtime.h>

#define TSEQ 1024
#define HIDV 64
#define NHEADS 16      // N*H = 2*8
#define LCH 64         // chunk length
#define NCH 16         // TSEQ/LCH
#define EMBED 512
#define CTX_FLOATS (NHEADS * TSEQ * HIDV)           // 1048576
#define PROBS_F4 ((size_t)4194304)                  // 16777216 floats / 4
#define EPSV 1e-6f
#define PIH 1.5707963267948966f

typedef short bf16x8 __attribute__((ext_vector_type(8)));
typedef float f32x4 __attribute__((ext_vector_type(4)));

__device__ __forceinline__ float relu_f(float x) { return fmaxf(x, 0.0f); }
__device__ __forceinline__ ushort f2bf(float f) {
    uint u = __float_as_uint(f);
    u += 0x7FFF + ((u >> 16) & 1);          // RNE
    return (ushort)(u >> 16);
}
__device__ __forceinline__ float bf2f(ushort h) { return __uint_as_float(((uint)h) << 16); }
__device__ __forceinline__ uint pk2(float a, float b) {
    return (uint)f2bf(a) | ((uint)f2bf(b) << 16);
}

// ---------------------------------------------------------------------------
// Kernel 1: per (b,c): S[dd][m] = sum_i kw[i][dd] * v[i][m]  (dd in 0..127,
// kw = [s_i relu(k), c_i relu(k)]), ksum[dd] = sum_i kw[i][dd].  MFMA bf16.
// grid 256 (b*16+c) x 512 threads.  Fuses probs-zero slice 0.
// ---------------------------------------------------------------------------
__global__ __launch_bounds__(512) void k_chunksum(
    const float* __restrict__ K, const float* __restrict__ V,
    float* __restrict__ Sws, float* __restrict__ ksumws,
    float4* __restrict__ probs4)
{
    __shared__ ushort kwT[128 * 72];   // [dd][i]  (A-operand layout, M=dd,K=i)
    __shared__ ushort vT[64 * 72];     // [m][i]   (B-operand layout, N=m,K=i)
    const int blk = blockIdx.x;
    const int b = blk >> 4, c = blk & 15;
    const int l0 = c * LCH;
    const int tid = threadIdx.x;

    // fused probs zeroing: slice 0 (f4 [0, 1048576))
    {
        float4 z = make_float4(0.f, 0.f, 0.f, 0.f);
        size_t zb = (size_t)blk * 4096 + tid;
        #pragma unroll
        for (int s = 0; s < 8; ++s) probs4[zb + s * 512] = z;
    }

    // stage K -> kwT (weighted, transposed), V -> vT (transposed)
    #pragma unroll
    for (int s = 0; s < 2; ++s) {
        int e = tid + s * 512;             // f4 index over 64x64
        int i = e >> 4, d = (e & 15) * 4;
        float4 k4 = *(const float4*)(K + (size_t)(b * TSEQ + l0 + i) * HIDV + d);
        float ang = PIH * (float)(l0 + i + 1) * (1.0f / 1024.0f);
        float si = sinf(ang), ci = cosf(ang);
        float kv[4] = {relu_f(k4.x), relu_f(k4.y), relu_f(k4.z), relu_f(k4.w)};
        #pragma unroll
        for (int j = 0; j < 4; ++j) {
            kwT[(d + j) * 72 + i] = f2bf(si * kv[j]);
            kwT[(d + 64 + j) * 72 + i] = f2bf(ci * kv[j]);
        }
        float4 v4 = *(const float4*)(V + ((size_t)(l0 + i) * NHEADS + b) * HIDV + d);
        float vv[4] = {v4.x, v4.y, v4.z, v4.w};
        #pragma unroll
        for (int j = 0; j < 4; ++j) vT[(d + j) * 72 + i] = f2bf(vv[j]);
    }
    __syncthreads();

    const int w = tid >> 6, lane = tid & 63;
    const int quad = lane >> 4, l15 = lane & 15;
    const int it = w;                     // dd-tile 0..7

    bf16x8 af[2];
    #pragma unroll
    for (int kk = 0; kk < 2; ++kk)
        af[kk] = *(const bf16x8*)(kwT + (it * 16 + l15) * 72 + kk * 32 + quad * 8);

    f32x4 acc[4];
    #pragma unroll
    for (int mt = 0; mt < 4; ++mt) {
        acc[mt] = (f32x4){0.f, 0.f, 0.f, 0.f};
        #pragma unroll
        for (int kk = 0; kk < 2; ++kk) {
            bf16x8 bf = *(const bf16x8*)(vT + (mt * 16 + l15) * 72 + kk * 32 + quad * 8);
            acc[mt] = __builtin_amdgcn_mfma_f32_16x16x32_bf16(af[kk], bf, acc[mt], 0, 0, 0);
        }
    }
    float* Sp = Sws + (size_t)blk * 8192;
    #pragma unroll
    for (int mt = 0; mt < 4; ++mt)
        #pragma unroll
        for (int r = 0; r < 4; ++r)
            Sp[(it * 16 + quad * 4 + r) * 64 + mt * 16 + l15] = acc[mt][r];

    if (tid < 128) {
        float s = 0.f;
        #pragma unroll
        for (int ss = 0; ss < 8; ++ss) {
            uint4 u = *(const uint4*)(kwT + tid * 72 + ss * 8);
            s += bf2f((ushort)(u.x & 0xffff)) + bf2f((ushort)(u.x >> 16));
            s += bf2f((ushort)(u.y & 0xffff)) + bf2f((ushort)(u.y >> 16));
            s += bf2f((ushort)(u.z & 0xffff)) + bf2f((ushort)(u.z >> 16));
            s += bf2f((ushort)(u.w & 0xffff)) + bf2f((ushort)(u.w >> 16));
        }
        ksumws[(size_t)blk * 128 + tid] = s;
    }
}

// ---------------------------------------------------------------------------
// Kernel 2: exclusive prefix scan over chunks (fp32).  Fuses probs slice 1.
// grid 512 x 256.
// ---------------------------------------------------------------------------
__global__ __launch_bounds__(256) void k_scan(
    float* __restrict__ Sws, float* __restrict__ ksumws,
    float4* __restrict__ probs4)
{
    {
        float4 z = make_float4(0.f, 0.f, 0.f, 0.f);
        size_t zb = 1048576 + (size_t)blockIdx.x * 2048 + threadIdx.x;
        #pragma unroll
        for (int s = 0; s < 8; ++s) probs4[zb + s * 256] = z;
    }
    int g = blockIdx.x * 256 + threadIdx.x;      // 0 .. 131071
    int b = g >> 13, idx = g & 8191;
    float acc = 0.0f;
    #pragma unroll
    for (int c = 0; c < NCH; ++c) {
        float* p = Sws + ((size_t)(b * NCH + c)) * 8192 + idx;
        float t = *p; *p = acc; acc += t;
    }
    if (g < NHEADS * 128) {
        int b2 = g >> 7, i2 = g & 127;
        float a2 = 0.0f;
        #pragma unroll
        for (int c = 0; c < NCH; ++c) {
            float* p = ksumws + (size_t)(b2 * NCH + c) * 128 + i2;
            float t = *p; *p = a2; a2 += t;
        }
    }
}

// ---------------------------------------------------------------------------
// Kernel 3: per (b,c): Am = tril(qw kw^T);  O = Am*V + qw*P;  den = rowsum(Am)
// + qw*psum;  write attn2 (T,N,512).  MFMA bf16.  grid 256 x 512.
// Fuses probs slice 2.
// ---------------------------------------------------------------------------
__global__ __launch_bounds__(512) void k_attn(
    const float* __restrict__ Q, const float* __restrict__ K,
    const float* __restrict__ V,
    const float* __restrict__ Sws, const float* __restrict__ ksumws,
    float* __restrict__ attn2, float4* __restrict__ probs4)
{
    __shared__ ushort qw[64 * 136];    // [i][dd]  A-layout
    __shared__ ushort kw[64 * 136];    // [j][dd]  B-layout (n=j, k=dd)
    __shared__ ushort Pt[64 * 136];    // [m][dd]  B-layout (n=m, k=dd)
    __shared__ ushort vT[64 * 72];     // [m][j]   B-layout (n=m, k=j)
    __shared__ ushort Am[64 * 72];     // [i][j]   A-layout (masked, bf16)
    __shared__ float psum[128], denA[64], denI[64];

    const int blk = blockIdx.x;
    const int b = blk >> 4, c = blk & 15;
    const int l0 = c * LCH;
    const int tid = threadIdx.x;

    {
        float4 z = make_float4(0.f, 0.f, 0.f, 0.f);
        size_t zb = 2097152 + (size_t)blk * 4096 + tid;
        #pragma unroll
        for (int s = 0; s < 8; ++s) probs4[zb + s * 512] = z;
    }
    if (tid < 64) denA[tid] = 0.f;

    // stage Q->qw, K->kw (weighted, row-major [row][128])
    #pragma unroll
    for (int s = 0; s < 2; ++s) {
        int e = tid + s * 512;
        int i = e >> 4, d = (e & 15) * 4;
        float ang = PIH * (float)(l0 + i + 1) * (1.0f / 1024.0f);
        float si = sinf(ang), ci = cosf(ang);
        float4 q4 = *(const float4*)(Q + (size_t)(b * TSEQ + l0 + i) * HIDV + d);
        float qv[4] = {relu_f(q4.x), relu_f(q4.y), relu_f(q4.z), relu_f(q4.w)};
        *(uint2*)(qw + i * 136 + d) = make_uint2(pk2(si * qv[0], si * qv[1]), pk2(si * qv[2], si * qv[3]));
        *(uint2*)(qw + i * 136 + 64 + d) = make_uint2(pk2(ci * qv[0], ci * qv[1]), pk2(ci * qv[2], ci * qv[3]));
        float4 k4 = *(const float4*)(K + (size_t)(b * TSEQ + l0 + i) * HIDV + d);
        float kv[4] = {relu_f(k4.x), relu_f(k4.y), relu_f(k4.z), relu_f(k4.w)};
        *(uint2*)(kw + i * 136 + d) = make_uint2(pk2(si * kv[0], si * kv[1]), pk2(si * kv[2], si * kv[3]));
        *(uint2*)(kw + i * 136 + 64 + d) = make_uint2(pk2(ci * kv[0], ci * kv[1]), pk2(ci * kv[2], ci * kv[3]));
        // V -> vT (transposed)
        float4 v4 = *(const float4*)(V + ((size_t)(l0 + i) * NHEADS + b) * HIDV + d);
        float vv[4] = {v4.x, v4.y, v4.z, v4.w};
        #pragma unroll
        for (int j = 0; j < 4; ++j) vT[(d + j) * 72 + i] = f2bf(vv[j]);
    }
    // stage P (exclusive prefix) transposed -> Pt[m][dd]
    {
        const float* Pg = Sws + (size_t)blk * 8192;     // [dd][m]
        #pragma unroll
        for (int s = 0; s < 4; ++s) {
            int e = tid + s * 512;                       // f4 over 128x64
            int dd = e >> 4, m = (e & 15) * 4;
            float4 p4 = *(const float4*)(Pg + dd * 64 + m);
            float pv[4] = {p4.x, p4.y, p4.z, p4.w};
            #pragma unroll
            for (int j = 0; j < 4; ++j) Pt[(m + j) * 136 + dd] = f2bf(pv[j]);
        }
        if (tid < 128) psum[tid] = ksumws[(size_t)blk * 128 + tid];
    }
    __syncthreads();

    const int w = tid >> 6, lane = tid & 63;
    const int quad = lane >> 4, l15 = lane & 15;
    const int it = w >> 1;                 // i-tile 0..3
    const int jb = (w & 1) * 2;            // j/m tile base

    // a-frags for rows it*16.. (K=128), reused for QK^T and qw*P
    bf16x8 af[4];
    #pragma unroll
    for (int kk = 0; kk < 4; ++kk)
        af[kk] = *(const bf16x8*)(qw + (it * 16 + l15) * 136 + kk * 32 + quad * 8);

    // Phase A: QK^T for 2 tiles
    f32x4 accA[2];
    #pragma unroll
    for (int jj = 0; jj < 2; ++jj) {
        accA[jj] = (f32x4){0.f, 0.f, 0.f, 0.f};
        #pragma unroll
        for (int kk = 0; kk < 4; ++kk) {
            bf16x8 bf = *(const bf16x8*)(kw + ((jb + jj) * 16 + l15) * 136 + kk * 32 + quad * 8);
            accA[jj] = __builtin_amdgcn_mfma_f32_16x16x32_bf16(af[kk], bf, accA[jj], 0, 0, 0);
        }
    }
    // mask (j<=i), write Am bf16, row-sums -> denA
    {
        float rsum[4] = {0.f, 0.f, 0.f, 0.f};
        #pragma unroll
        for (int jj = 0; jj < 2; ++jj) {
            int j = (jb + jj) * 16 + l15;
            #pragma unroll
            for (int r = 0; r < 4; ++r) {
                int i = it * 16 + quad * 4 + r;
                float val = (j <= i) ? accA[jj][r] : 0.f;
                Am[i * 72 + j] = f2bf(val);
                rsum[r] += val;
            }
        }
        #pragma unroll
        for (int off = 1; off < 16; off <<= 1) {
            rsum[0] += __shfl_xor(rsum[0], off);
            rsum[1] += __shfl_xor(rsum[1], off);
            rsum[2] += __shfl_xor(rsum[2], off);
            rsum[3] += __shfl_xor(rsum[3], off);
        }
        if (l15 == 0) {
            #pragma unroll
            for (int r = 0; r < 4; ++r)
                atomicAdd(&denA[it * 16 + quad * 4 + r], rsum[r]);
        }
    }
    // denI[i] = qw[i] . psum  (threads 0..63)
    if (tid < 64) {
        float s = 0.f;
        #pragma unroll
        for (int ss = 0; ss < 16; ++ss) {
            uint4 u = *(const uint4*)(qw + tid * 136 + ss * 8);
            s += bf2f((ushort)(u.x & 0xffff)) * psum[ss * 8 + 0] + bf2f((ushort)(u.x >> 16)) * psum[ss * 8 + 1];
            s += bf2f((ushort)(u.y & 0xffff)) * psum[ss * 8 + 2] + bf2f((ushort)(u.y >> 16)) * psum[ss * 8 + 3];
            s += bf2f((ushort)(u.z & 0xffff)) * psum[ss * 8 + 4] + bf2f((ushort)(u.z >> 16)) * psum[ss * 8 + 5];
            s += bf2f((ushort)(u.w & 0xffff)) * psum[ss * 8 + 6] + bf2f((ushort)(u.w >> 16)) * psum[ss * 8 + 7];
        }
        denI[tid] = s;
    }
    __syncthreads();

    // Phase B: O = qw*P (inter) + Am*V (intra), 2 m-tiles
    f32x4 accO[2];
    #pragma unroll
    for (int mm = 0; mm < 2; ++mm) {
        accO[mm] = (f32x4){0.f, 0.f, 0.f, 0.f};
        #pragma unroll
        for (int kk = 0; kk < 4; ++kk) {
            bf16x8 bp = *(const bf16x8*)(Pt + ((jb + mm) * 16 + l15) * 136 + kk * 32 + quad * 8);
            accO[mm] = __builtin_amdgcn_mfma_f32_16x16x32_bf16(af[kk], bp, accO[mm], 0, 0, 0);
        }
    }
    bf16x8 aA[2];
    #pragma unroll
    for (int kk = 0; kk < 2; ++kk)
        aA[kk] = *(const bf16x8*)(Am + (it * 16 + l15) * 72 + kk * 32 + quad * 8);
    #pragma unroll
    for (int mm = 0; mm < 2; ++mm)
        #pragma unroll
        for (int kk = 0; kk < 2; ++kk) {
            bf16x8 bv = *(const bf16x8*)(vT + ((jb + mm) * 16 + l15) * 72 + kk * 32 + quad * 8);
            accO[mm] = __builtin_amdgcn_mfma_f32_16x16x32_bf16(aA[kk], bv, accO[mm], 0, 0, 0);
        }

    // epilogue: divide + store
    const int nb = b >> 3, hh = b & 7;
    #pragma unroll
    for (int r = 0; r < 4; ++r) {
        int i = it * 16 + quad * 4 + r;
        float inv = 1.0f / fmaxf(denA[i] + denI[i], EPSV);
        #pragma unroll
        for (int mm = 0; mm < 2; ++mm) {
            int m = (jb + mm) * 16 + l15;
            size_t row = (size_t)((l0 + i) * 2 + nb);
            attn2[row * EMBED + hh * 64 + m] = accO[mm][r] * inv;
        }
    }
}

// ---------------------------------------------------------------------------
// Kernel 4: out projection, MFMA bf16: out[r][e] = attn2[r][:] . W[e][:] + b[e]
// grid (32,8) 64x64 tiles, 256 threads.  Fuses probs slice 3.
// ---------------------------------------------------------------------------
__global__ __launch_bounds__(256) void k_outproj(
    const float* __restrict__ A2, const float* __restrict__ W,
    const float* __restrict__ bias, float* __restrict__ ctx,
    float4* __restrict__ probs4)
{
    __shared__ ushort Ab[64 * 72];   // [r][f]
    __shared__ ushort Bb[64 * 72];   // [e][f]
    const int r0 = blockIdx.x * 64;
    const int e0 = blockIdx.y * 64;
    const int tid = threadIdx.x;
    const int blin = blockIdx.y * 32 + blockIdx.x;

    {
        float4 z = make_float4(0.f, 0.f, 0.f, 0.f);
        size_t zb = 3145728 + (size_t)blin * 4096 + tid;
        #pragma unroll
        for (int s = 0; s < 16; ++s) probs4[zb + s * 256] = z;
    }

    const int w = tid >> 6, lane = tid & 63;
    const int quad = lane >> 4, l15 = lane & 15;
    const int it = w;
    f32x4 acc[4];
    #pragma unroll
    for (int jt = 0; jt < 4; ++jt) acc[jt] = (f32x4){0.f, 0.f, 0.f, 0.f};

    for (int f0 = 0; f0 < EMBED; f0 += 64) {
        __syncthreads();
        #pragma unroll
        for (int s = 0; s < 4; ++s) {
            int e = tid + s * 256;               // f4 over 64x64
            int rr = e >> 4, ff = (e & 15) * 4;
            float4 a4 = *(const float4*)(A2 + (size_t)(r0 + rr) * EMBED + f0 + ff);
            *(uint2*)(Ab + rr * 72 + ff) = make_uint2(pk2(a4.x, a4.y), pk2(a4.z, a4.w));
            float4 w4 = *(const float4*)(W + (size_t)(e0 + rr) * EMBED + f0 + ff);
            *(uint2*)(Bb + rr * 72 + ff) = make_uint2(pk2(w4.x, w4.y), pk2(w4.z, w4.w));
        }
        __syncthreads();
        bf16x8 af[2];
        #pragma unroll
        for (int kk = 0; kk < 2; ++kk)
            af[kk] = *(const bf16x8*)(Ab + (it * 16 + l15) * 72 + kk * 32 + quad * 8);
        #pragma unroll
        for (int jt = 0; jt < 4; ++jt)
            #pragma unroll
            for (int kk = 0; kk < 2; ++kk) {
                bf16x8 bf = *(const bf16x8*)(Bb + (jt * 16 + l15) * 72 + kk * 32 + quad * 8);
                acc[jt] = __builtin_amdgcn_mfma_f32_16x16x32_bf16(af[kk], bf, acc[jt], 0, 0, 0);
            }
    }
    #pragma unroll
    for (int jt = 0; jt < 4; ++jt) {
        int e = e0 + jt * 16 + l15;
        float be = bias[e];
        int h = e >> 6, m = e & 63;
        #pragma unroll
        for (int r = 0; r < 4; ++r) {
            int rr = r0 + it * 16 + quad * 4 + r;
            int t = rr >> 1, n = rr & 1;
            ctx[((size_t)(n * 8 + h) * TSEQ + t) * HIDV + m] = acc[jt][r] + be;
        }
    }
}

// ---------------------------------------------------------------------------
extern "C" void kernel_launch(void* const* d_in, const int* in_sizes, int n_in,
                              void* d_out, int out_size, void* d_ws, size_t ws_size,
                              hipStream_t stream) {
    const float* q = (const float*)d_in[0];
    const float* k = (const float*)d_in[1];
    const float* v = (const float*)d_in[2];
    const float* W = (const float*)d_in[3];
    const float* bias = (const float*)d_in[4];
    float* out = (float*)d_out;
    float* ws = (float*)d_ws;

    float* S_ws = ws;                         // 16*16*8192 = 2097152 floats
    float* ksum_ws = ws + 2097152;            // 16*16*128  = 32768 floats
    float* attn2 = ws + 2097152 + 32768;      // 2048*512   = 1048576 floats
    float4* probs4 = (float4*)(out + CTX_FLOATS);

    k_chunksum<<<dim3(256), dim3(512), 0, stream>>>(k, v, S_ws, ksum_ws, probs4);
    k_scan<<<dim3(512), dim3(256), 0, stream>>>(S_ws, ksum_ws, probs4);
    k_attn<<<dim3(256), dim3(512), 0, stream>>>(q, k, v, S_ws, ksum_ws, attn2, probs4);
    k_outproj<<<dim3(32, 8), dim3(256), 0, stream>>>(attn2, W, bias, out, probs4);
}